// Round 5
// baseline (2142.963 us; speedup 1.0000x reference)
//
#include <hip/hip_runtime.h>
#include <stdint.h>

#define B 64
#define S 512
#define E 512
#define H 1024
#define NCLS 4

typedef __attribute__((ext_vector_type(8))) short short8;
typedef __attribute__((ext_vector_type(4))) float f32x4;

__device__ __forceinline__ unsigned short f32_to_bf16(float f) {
    unsigned int x = __float_as_uint(f);
    unsigned int r = (x + 0x7fffu + ((x >> 16) & 1u)) >> 16;   // RNE
    return (unsigned short)r;
}
__device__ __forceinline__ float bf16_to_f32(unsigned short u) {
    return __uint_as_float(((unsigned int)u) << 16);
}

// write-through store (L1+L2 bypass -> MALL coherence point)
__device__ __forceinline__ void store_sc4u(unsigned int* p, unsigned int v) {
    asm volatile("global_store_dword %0, %1, off sc0 sc1"
                 :: "v"(p), "v"(v) : "memory");
}

// ---------------------------------------------------------------------------
// K1: wx[s][b][j] = sum_k emb[x[b*S+s]][k] * W[j][k] + b_w[j], stored bf16.
// (unchanged; ~57 us)
// ---------------------------------------------------------------------------
#define K1_LDA 40

__global__ __launch_bounds__(256) void k_wx_gemm(
    const int* __restrict__ x, const float* __restrict__ emb,
    const float* __restrict__ W, const float* __restrict__ bw,
    unsigned short* __restrict__ wx)
{
    __shared__ unsigned short Asub[128 * K1_LDA];
    __shared__ unsigned short Bsub[128 * K1_LDA];

    const int t  = threadIdx.x;
    const int mt = blockIdx.x;
    const int nt = blockIdx.y;
    const int i0 = mt * 128;
    const int j0 = nt * 128;

    const int r  = t >> 1;
    const int kh = (t & 1) * 16;
    const int tok = x[i0 + r];
    const float* arow = emb + (size_t)tok * E;
    const float* brow = W + (size_t)(j0 + r) * E;

    const int lane = t & 63;
    const int w    = t >> 6;
    const int wm   = (w >> 1) * 64;
    const int wn   = (w & 1) * 64;
    const int fr   = lane & 15;
    const int kg   = lane >> 4;

    f32x4 acc[4][4] = {};

    for (int kt = 0; kt < E; kt += 32) {
        __syncthreads();
        {
            union { unsigned short us[8]; uint4 v; } p;
            const float* srcA = arow + kt + kh;
            #pragma unroll
            for (int i = 0; i < 8; ++i) p.us[i] = f32_to_bf16(srcA[i]);
            *(uint4*)&Asub[r * K1_LDA + kh] = p.v;
            #pragma unroll
            for (int i = 0; i < 8; ++i) p.us[i] = f32_to_bf16(srcA[8 + i]);
            *(uint4*)&Asub[r * K1_LDA + kh + 8] = p.v;
            const float* srcB = brow + kt + kh;
            #pragma unroll
            for (int i = 0; i < 8; ++i) p.us[i] = f32_to_bf16(srcB[i]);
            *(uint4*)&Bsub[r * K1_LDA + kh] = p.v;
            #pragma unroll
            for (int i = 0; i < 8; ++i) p.us[i] = f32_to_bf16(srcB[8 + i]);
            *(uint4*)&Bsub[r * K1_LDA + kh + 8] = p.v;
        }
        __syncthreads();

        short8 a[4], b[4];
        #pragma unroll
        for (int mi = 0; mi < 4; ++mi)
            a[mi] = *(const short8*)&Asub[(wm + mi * 16 + fr) * K1_LDA + kg * 8];
        #pragma unroll
        for (int ni = 0; ni < 4; ++ni)
            b[ni] = *(const short8*)&Bsub[(wn + ni * 16 + fr) * K1_LDA + kg * 8];
        #pragma unroll
        for (int mi = 0; mi < 4; ++mi)
            #pragma unroll
            for (int ni = 0; ni < 4; ++ni)
                acc[mi][ni] = __builtin_amdgcn_mfma_f32_16x16x32_bf16(
                                  a[mi], b[ni], acc[mi][ni], 0, 0, 0);
    }

    float bwv[4];
    #pragma unroll
    for (int ni = 0; ni < 4; ++ni) bwv[ni] = bw[j0 + wn + ni * 16 + fr];
    #pragma unroll
    for (int mi = 0; mi < 4; ++mi) {
        #pragma unroll
        for (int ni = 0; ni < 4; ++ni) {
            const int gn = j0 + wn + ni * 16 + fr;
            #pragma unroll
            for (int rr = 0; rr < 4; ++rr) {
                const int gm = i0 + wm + mi * 16 + kg * 4 + rr;
                const int bb = gm >> 9;
                const int ss = gm & 511;
                wx[(size_t)(ss * B + bb) * H + gn] =
                    f32_to_bf16(acc[mi][ni][rr] + bwv[ni]);
            }
        }
    }
}

// ---------------------------------------------------------------------------
// K2: persistent recurrence, MFMA, bf16-U + split-bf16-h, tag-bit protocol.
//  - 8 groups x 32 members (1 wg/CU). Member m owns j rows [32m, 32m+32).
//  - U resident in LDS as ONE bf16 plane (64 KB), XOR-swizzled.
//  - h travels packed (bf16hi<<16)|bf16lo; LSB of lo carries step tag
//    tag(s) = ((s+1)>>1)&1 -> consumers poll their own data words; NO flags,
//    NO vmcnt drain on publish (fire-and-forget write-through stores).
//  - Per step: tagged poll+stage -> bar -> 32 MFMA/wave (2 split terms) ->
//    bar -> redC reduce -> bar -> tanh -> tagged publish -> bar.
//  - LDS: 64K U + 16K Hhi + 16K Hlo = 98304 B.
// ---------------------------------------------------------------------------
__global__ __launch_bounds__(256) void k_rnn(
    const unsigned short* __restrict__ wx, const float* __restrict__ U,
    const float* __restrict__ Vw, const float* __restrict__ bv,
    unsigned int* __restrict__ hbuf, float* __restrict__ out)
{
    __shared__ __align__(16) unsigned short Uhi[32 * 1024];  // 64 KB
    __shared__ __align__(16) unsigned short Hhi[8 * 1024];   // 16 KB
    __shared__ __align__(16) unsigned short Hlo[8 * 1024];   // 16 KB

    const int t   = threadIdx.x;
    const int g   = blockIdx.x & 7;      // group: batches [8g, 8g+8)
    const int m   = blockIdx.x >> 3;     // member: j rows [32m, 32m+32)
    const int j0  = m * 32;
    const int bg0 = g * 8;

    // ---- stage U -> bf16 plane, swizzled (byte ^= (row&7)<<4) ----
    for (int rr = 0; rr < 32; ++rr) {
        f32x4 v = *(const f32x4*)(U + (size_t)(j0 + rr) * H + t * 4);
        uint2 hwd;
        hwd.x = f32_to_bf16(v[0]) | ((unsigned)f32_to_bf16(v[1]) << 16);
        hwd.y = f32_to_bf16(v[2]) | ((unsigned)f32_to_bf16(v[3]) << 16);
        const int byteoff = (rr * 2048 + t * 8) ^ ((rr & 7) << 4);
        *(uint2*)((char*)Uhi + byteoff) = hwd;
    }

    // role constants
    const int lane  = t & 63;
    const int w     = t >> 6;            // wave id = K-chunk (256 k each)
    const int fr    = lane & 15;
    const int kg    = lane >> 4;         // 0..3
    const int kbase = w * 256;
    const int abrow = fr & 7;            // A (h) row: batches 8-15 dup 0-7
    const int ob    = t >> 5;            // output batch 0..7
    const int oj    = t & 31;            // output j local 0..31

    float* redC = (float*)Hhi;           // 4 KB reduce buffer (time-aliased)
    unsigned int* Hh32 = (unsigned int*)Hhi;
    unsigned int* Hl32 = (unsigned int*)Hlo;

    float wxv = bf16_to_f32(wx[(size_t)(bg0 + ob) * H + j0 + oj]);

    __syncthreads();                     // U resident

    for (int ts = 0; ts < S; ++ts) {
        const unsigned int* hr = hbuf + (ts & 1) * (B * H);
        unsigned int*       hw = hbuf + ((ts + 1) & 1) * (B * H);
        const unsigned int exp  = ((unsigned)(ts + 1) >> 1) & 1u;  // tag(ts)
        const unsigned int ptag = ((unsigned)(ts + 2) >> 1) & 1u;  // tag(ts+1)

        // ---- tagged poll + stage: 16 u64 MALL loads, retry stragglers ----
        const unsigned long long* src =
            (const unsigned long long*)(hr + (size_t)(bg0 + ob) * H);
        unsigned long long vv[16];
        #pragma unroll
        for (int i = 0; i < 16; ++i)
            vv[i] = __hip_atomic_load(src + oj + 32 * i, __ATOMIC_RELAXED,
                                      __HIP_MEMORY_SCOPE_AGENT);

        // prefetch next step's wx (h-independent, cached)
        float wx_next = 0.f;
        if (ts + 1 < S)
            wx_next = bf16_to_f32(wx[(size_t)((ts + 1) * B + bg0 + ob) * H + j0 + oj]);

        #pragma unroll
        for (int i = 0; i < 16; ++i) {
            while ((((unsigned int)vv[i] ^ exp) |
                    ((unsigned int)(vv[i] >> 32) ^ exp)) & 1u)
                vv[i] = __hip_atomic_load(src + oj + 32 * i, __ATOMIC_RELAXED,
                                          __HIP_MEMORY_SCOPE_AGENT);
            const unsigned int v0 = (unsigned int)vv[i];
            const unsigned int v1 = (unsigned int)(vv[i] >> 32);
            const int idx = (ob * 512 + oj + 32 * i) ^ (ob << 2);
            Hh32[idx] = (v0 >> 16) | (v1 & 0xffff0000u);
            Hl32[idx] = (v0 & 0xffffu) | (v1 << 16);
        }
        __syncthreads();                 // bar1: H planes resident

        // ---- MFMA: C[16b x 32j] over this wave's K-chunk, 2 split terms ----
        f32x4 acc0 = {}, acc1 = {};
        #pragma unroll
        for (int kk = 0; kk < 8; ++kk) {
            const int k  = kbase + kk * 32 + kg * 8;
            const int ab = (abrow * 2048 + k * 2) ^ (abrow << 4);
            const short8 ahi = *(const short8*)((const char*)Hhi + ab);
            const short8 alo = *(const short8*)((const char*)Hlo + ab);
            const int b0 = (fr * 2048 + k * 2) ^ ((fr & 7) << 4);
            const int b1 = ((16 + fr) * 2048 + k * 2) ^ ((fr & 7) << 4);
            const short8 bhi0 = *(const short8*)((const char*)Uhi + b0);
            const short8 bhi1 = *(const short8*)((const char*)Uhi + b1);
            acc0 = __builtin_amdgcn_mfma_f32_16x16x32_bf16(ahi, bhi0, acc0, 0, 0, 0);
            acc0 = __builtin_amdgcn_mfma_f32_16x16x32_bf16(alo, bhi0, acc0, 0, 0, 0);
            acc1 = __builtin_amdgcn_mfma_f32_16x16x32_bf16(ahi, bhi1, acc1, 0, 0, 0);
            acc1 = __builtin_amdgcn_mfma_f32_16x16x32_bf16(alo, bhi1, acc1, 0, 0, 0);
        }
        __syncthreads();                 // bar2: H/U reads done before redC alias

        // ---- cross-wave K-reduction via LDS ----
        if (kg < 2) {
            #pragma unroll
            for (int rr = 0; rr < 4; ++rr) {
                const int mb = kg * 4 + rr;          // batch row 0..7
                redC[w * 256 + mb * 32 + fr]      = acc0[rr];
                redC[w * 256 + mb * 32 + 16 + fr] = acc1[rr];
            }
        }
        __syncthreads();                 // bar3

        float sum = redC[      ob * 32 + oj] + redC[256 + ob * 32 + oj]
                  + redC[512 + ob * 32 + oj] + redC[768 + ob * 32 + oj];

        float p = wxv + sum;
        p = fminf(fmaxf(p, -15.f), 15.f);
        const float e  = __expf(2.0f * p);
        const float hv = 1.0f - 2.0f / (e + 1.0f);

        // pack hi|lo, stamp tag in lo LSB, fire-and-forget publish
        const unsigned short hib = f32_to_bf16(hv);
        const unsigned short lob = f32_to_bf16(hv - bf16_to_f32(hib));
        unsigned int pk = ((unsigned int)hib << 16) | lob;
        pk = (pk & ~1u) | ptag;
        store_sc4u(hw + (size_t)(bg0 + ob) * H + j0 + oj, pk);

        __syncthreads();                 // bar4: redC reads done before next stage
        wxv = wx_next;
    }

    // ---- final projection: out[b][c] = h_final[b] . V[c] + bv[c] ----
    if (m == 0) {
        const unsigned int expf_ = ((unsigned)(S + 1) >> 1) & 1u;  // tag(512)=0
        const unsigned int* hf = hbuf;   // S even -> final state in buf0
        const int o = t & 31, part = t >> 5;
        const int pb = o >> 2, c = o & 3;
        const unsigned long long* hrow =
            (const unsigned long long*)(hf + (size_t)(bg0 + pb) * H) + part * 64;
        const float* vrow = Vw + (size_t)c * H + part * 128;
        float partial = 0.f;
        for (int q = 0; q < 64; ++q) {
            unsigned long long vvq = __hip_atomic_load(hrow + q, __ATOMIC_RELAXED,
                                                       __HIP_MEMORY_SCOPE_AGENT);
            while ((((unsigned int)vvq ^ expf_) |
                    ((unsigned int)(vvq >> 32) ^ expf_)) & 1u)
                vvq = __hip_atomic_load(hrow + q, __ATOMIC_RELAXED,
                                        __HIP_MEMORY_SCOPE_AGENT);
            const unsigned int v0 = (unsigned int)vvq;
            const unsigned int v1 = (unsigned int)(vvq >> 32);
            const float h0 = bf16_to_f32((unsigned short)(v0 >> 16))
                           + bf16_to_f32((unsigned short)(v0 & 0xffffu));
            const float h1 = bf16_to_f32((unsigned short)(v1 >> 16))
                           + bf16_to_f32((unsigned short)(v1 & 0xffffu));
            partial += h0 * vrow[2 * q] + h1 * vrow[2 * q + 1];
        }
        __syncthreads();
        redC[part * 32 + o] = partial;
        __syncthreads();
        if (t < 32) {
            float sv = 0.f;
            #pragma unroll
            for (int pq = 0; pq < 8; ++pq) sv += redC[pq * 32 + t];
            out[(bg0 + (t >> 2)) * NCLS + (t & 3)] = sv + bv[t & 3];
        }
    }
}

// ---------------------------------------------------------------------------
extern "C" void kernel_launch(void* const* d_in, const int* in_sizes, int n_in,
                              void* d_out, int out_size, void* d_ws, size_t ws_size,
                              hipStream_t stream)
{
    const int*   x   = (const int*)d_in[0];
    const float* emb = (const float*)d_in[1];
    const float* W   = (const float*)d_in[2];
    const float* bw  = (const float*)d_in[3];
    const float* U   = (const float*)d_in[4];
    const float* V   = (const float*)d_in[5];
    const float* bv  = (const float*)d_in[6];
    float* out = (float*)d_out;

    unsigned short* wx = (unsigned short*)d_ws;
    const size_t WX_BYTES = (size_t)S * B * H * sizeof(unsigned short); // 64 MiB
    unsigned int* hbuf = (unsigned int*)((char*)d_ws + WX_BYTES);
    const size_t HB_BYTES = (size_t)2 * B * H * sizeof(unsigned int);   // 512 KiB

    // zero both h buffers every call: gives h0 = 0 AND correct initial tags
    hipMemsetAsync((char*)d_ws + WX_BYTES, 0, HB_BYTES, stream);

    hipLaunchKernelGGL(k_wx_gemm, dim3(256, 8), dim3(256), 0, stream,
                       x, emb, W, bw, wx);
    hipLaunchKernelGGL(k_rnn, dim3(256), dim3(256), 0, stream,
                       wx, U, V, bv, hbuf, out);
}

// Round 6
// 2106.095 us; speedup vs baseline: 1.0175x; 1.0175x over previous
//
#include <hip/hip_runtime.h>
#include <stdint.h>

#define B 64
#define S 512
#define E 512
#define H 1024
#define NCLS 4

typedef __attribute__((ext_vector_type(8))) short short8;
typedef __attribute__((ext_vector_type(4))) float f32x4;

__device__ __forceinline__ unsigned short f32_to_bf16(float f) {
    unsigned int x = __float_as_uint(f);
    unsigned int r = (x + 0x7fffu + ((x >> 16) & 1u)) >> 16;   // RNE
    return (unsigned short)r;
}
__device__ __forceinline__ float bf16_to_f32(unsigned short u) {
    return __uint_as_float(((unsigned int)u) << 16);
}

// write-through store (L1+L2 bypass -> MALL coherence point)
__device__ __forceinline__ void store_sc4u(unsigned int* p, unsigned int v) {
    asm volatile("global_store_dword %0, %1, off sc0 sc1"
                 :: "v"(p), "v"(v) : "memory");
}

// ---------------------------------------------------------------------------
// K1: wx[s][b][j] = sum_k emb[x[b*S+s]][k] * W[j][k] + b_w[j], stored bf16.
// (unchanged; ~57 us)
// ---------------------------------------------------------------------------
#define K1_LDA 40

__global__ __launch_bounds__(256) void k_wx_gemm(
    const int* __restrict__ x, const float* __restrict__ emb,
    const float* __restrict__ W, const float* __restrict__ bw,
    unsigned short* __restrict__ wx)
{
    __shared__ unsigned short Asub[128 * K1_LDA];
    __shared__ unsigned short Bsub[128 * K1_LDA];

    const int t  = threadIdx.x;
    const int mt = blockIdx.x;
    const int nt = blockIdx.y;
    const int i0 = mt * 128;
    const int j0 = nt * 128;

    const int r  = t >> 1;
    const int kh = (t & 1) * 16;
    const int tok = x[i0 + r];
    const float* arow = emb + (size_t)tok * E;
    const float* brow = W + (size_t)(j0 + r) * E;

    const int lane = t & 63;
    const int w    = t >> 6;
    const int wm   = (w >> 1) * 64;
    const int wn   = (w & 1) * 64;
    const int fr   = lane & 15;
    const int kg   = lane >> 4;

    f32x4 acc[4][4] = {};

    for (int kt = 0; kt < E; kt += 32) {
        __syncthreads();
        {
            union { unsigned short us[8]; uint4 v; } p;
            const float* srcA = arow + kt + kh;
            #pragma unroll
            for (int i = 0; i < 8; ++i) p.us[i] = f32_to_bf16(srcA[i]);
            *(uint4*)&Asub[r * K1_LDA + kh] = p.v;
            #pragma unroll
            for (int i = 0; i < 8; ++i) p.us[i] = f32_to_bf16(srcA[8 + i]);
            *(uint4*)&Asub[r * K1_LDA + kh + 8] = p.v;
            const float* srcB = brow + kt + kh;
            #pragma unroll
            for (int i = 0; i < 8; ++i) p.us[i] = f32_to_bf16(srcB[i]);
            *(uint4*)&Bsub[r * K1_LDA + kh] = p.v;
            #pragma unroll
            for (int i = 0; i < 8; ++i) p.us[i] = f32_to_bf16(srcB[8 + i]);
            *(uint4*)&Bsub[r * K1_LDA + kh + 8] = p.v;
        }
        __syncthreads();

        short8 a[4], b[4];
        #pragma unroll
        for (int mi = 0; mi < 4; ++mi)
            a[mi] = *(const short8*)&Asub[(wm + mi * 16 + fr) * K1_LDA + kg * 8];
        #pragma unroll
        for (int ni = 0; ni < 4; ++ni)
            b[ni] = *(const short8*)&Bsub[(wn + ni * 16 + fr) * K1_LDA + kg * 8];
        #pragma unroll
        for (int mi = 0; mi < 4; ++mi)
            #pragma unroll
            for (int ni = 0; ni < 4; ++ni)
                acc[mi][ni] = __builtin_amdgcn_mfma_f32_16x16x32_bf16(
                                  a[mi], b[ni], acc[mi][ni], 0, 0, 0);
    }

    float bwv[4];
    #pragma unroll
    for (int ni = 0; ni < 4; ++ni) bwv[ni] = bw[j0 + wn + ni * 16 + fr];
    #pragma unroll
    for (int mi = 0; mi < 4; ++mi) {
        #pragma unroll
        for (int ni = 0; ni < 4; ++ni) {
            const int gn = j0 + wn + ni * 16 + fr;
            #pragma unroll
            for (int rr = 0; rr < 4; ++rr) {
                const int gm = i0 + wm + mi * 16 + kg * 4 + rr;
                const int bb = gm >> 9;
                const int ss = gm & 511;
                wx[(size_t)(ss * B + bb) * H + gn] =
                    f32_to_bf16(acc[mi][ni][rr] + bwv[ni]);
            }
        }
    }
}

// ---------------------------------------------------------------------------
// K2: persistent recurrence. MFMA, bf16-U + split-bf16-h, tag-bit protocol,
// wave-private staging, ONE barrier per step.
//  - 8 groups x 32 members (1 wg/CU). Member m owns j rows [32m, 32m+32).
//  - Wave w stages+consumes ONLY k in [256w, 256w+256) (members [8w,8w+8))
//    -> stage->MFMA is wave-private, no barrier; per-wave straggler decouple.
//  - Multi-pass parallel tag-poll: issue ALL pending loads per pass (one
//    batched MALL round-trip), never serial per-word retry chains.
//  - redC double-buffered (ts&1) -> only barrier left is post-redC-write;
//    it also transitively guards the h double-buffer WAR across wgs.
//  - LDS: 64K U + 16K Hhi + 16K Hlo + 2x4K redC = 104 KB (1 wg/CU).
// ---------------------------------------------------------------------------
__global__ __launch_bounds__(256) void k_rnn(
    const unsigned short* __restrict__ wx, const float* __restrict__ U,
    const float* __restrict__ Vw, const float* __restrict__ bv,
    unsigned int* __restrict__ hbuf, float* __restrict__ out)
{
    __shared__ __align__(16) unsigned short Uhi[32 * 1024];  // 64 KB
    __shared__ __align__(16) unsigned short Hhi[8 * 1024];   // 16 KB
    __shared__ __align__(16) unsigned short Hlo[8 * 1024];   // 16 KB
    __shared__ __align__(16) float redCA[1024];              //  4 KB
    __shared__ __align__(16) float redCB[1024];              //  4 KB

    const int t   = threadIdx.x;
    const int g   = blockIdx.x & 7;      // group: batches [8g, 8g+8)
    const int m   = blockIdx.x >> 3;     // member: j rows [32m, 32m+32)
    const int j0  = m * 32;
    const int bg0 = g * 8;

    // ---- stage U -> bf16 plane, swizzled (byte ^= (row&7)<<4) ----
    for (int rr = 0; rr < 32; ++rr) {
        f32x4 v = *(const f32x4*)(U + (size_t)(j0 + rr) * H + t * 4);
        uint2 hwd;
        hwd.x = f32_to_bf16(v[0]) | ((unsigned)f32_to_bf16(v[1]) << 16);
        hwd.y = f32_to_bf16(v[2]) | ((unsigned)f32_to_bf16(v[3]) << 16);
        const int byteoff = (rr * 2048 + t * 8) ^ ((rr & 7) << 4);
        *(uint2*)((char*)Uhi + byteoff) = hwd;
    }

    // role constants
    const int lane  = t & 63;
    const int w     = t >> 6;            // wave id = K-chunk (256 k each)
    const int fr    = lane & 15;
    const int kg    = lane >> 4;         // 0..3
    const int kbase = w * 256;
    const int abrow = fr & 7;            // A (h) row: batches 8-15 dup 0-7
    const int ob    = t >> 5;            // output batch 0..7
    const int oj    = t & 31;            // output j local 0..31

    unsigned int* Hh32 = (unsigned int*)Hhi;
    unsigned int* Hl32 = (unsigned int*)Hlo;

    float wxv = bf16_to_f32(wx[(size_t)(bg0 + ob) * H + j0 + oj]);

    __syncthreads();                     // U resident

    for (int ts = 0; ts < S; ++ts) {
        const unsigned int* hr = hbuf + (ts & 1) * (B * H);
        unsigned int*       hw = hbuf + ((ts + 1) & 1) * (B * H);
        float* redCp = (ts & 1) ? redCB : redCA;
        const unsigned int etag = ((unsigned)(ts + 1) >> 1) & 1u;  // tag(ts)
        const unsigned int ptag = ((unsigned)(ts + 2) >> 1) & 1u;  // tag(ts+1)

        // prefetch next step's wx (h-independent, cached)
        float wx_next = 0.f;
        if (ts + 1 < S)
            wx_next = bf16_to_f32(wx[(size_t)((ts + 1) * B + bg0 + ob) * H + j0 + oj]);

        // ---- wave-private tagged poll + stage of k-chunk [256w, 256w+256) --
        // lane covers 16 u64 words: li = lane + 64*i over [8 batch][128 col]
        {
            const unsigned long long* hb64 = (const unsigned long long*)hr;
            unsigned long long vv[16];
            unsigned int pend = 0xffffu;
            do {
                #pragma unroll
                for (int i = 0; i < 16; ++i) {
                    if (pend & (1u << i)) {
                        const int li  = lane + 64 * i;
                        const int b   = li >> 7;
                        const int col = li & 127;
                        vv[i] = __hip_atomic_load(
                            hb64 + (size_t)(bg0 + b) * 512 + w * 128 + col,
                            __ATOMIC_RELAXED, __HIP_MEMORY_SCOPE_AGENT);
                    }
                }
                #pragma unroll
                for (int i = 0; i < 16; ++i) {
                    if (pend & (1u << i)) {
                        const unsigned int v0 = (unsigned int)vv[i];
                        const unsigned int v1 = (unsigned int)(vv[i] >> 32);
                        if (!(((v0 ^ etag) | (v1 ^ etag)) & 1u)) {
                            const int li  = lane + 64 * i;
                            const int b   = li >> 7;
                            const int k2  = w * 128 + (li & 127);
                            const int idx = (b * 512 + k2) ^ (b << 2);
                            Hh32[idx] = (v0 >> 16) | (v1 & 0xffff0000u);
                            Hl32[idx] = (v0 & 0xffffu) | (v1 << 16);
                            pend &= ~(1u << i);
                        }
                    }
                }
            } while (pend);
        }
        // no barrier: wave w's MFMA reads only its own staged k-chunk

        // ---- MFMA: C[16b x 32j] over this wave's K-chunk, 2 split terms ----
        f32x4 acc0 = {}, acc1 = {};
        #pragma unroll
        for (int kk = 0; kk < 8; ++kk) {
            const int k  = kbase + kk * 32 + kg * 8;
            const int ab = (abrow * 2048 + k * 2) ^ (abrow << 4);
            const short8 ahi = *(const short8*)((const char*)Hhi + ab);
            const short8 alo = *(const short8*)((const char*)Hlo + ab);
            const int b0 = (fr * 2048 + k * 2) ^ ((fr & 7) << 4);
            const int b1 = ((16 + fr) * 2048 + k * 2) ^ ((fr & 7) << 4);
            const short8 bhi0 = *(const short8*)((const char*)Uhi + b0);
            const short8 bhi1 = *(const short8*)((const char*)Uhi + b1);
            acc0 = __builtin_amdgcn_mfma_f32_16x16x32_bf16(ahi, bhi0, acc0, 0, 0, 0);
            acc0 = __builtin_amdgcn_mfma_f32_16x16x32_bf16(alo, bhi0, acc0, 0, 0, 0);
            acc1 = __builtin_amdgcn_mfma_f32_16x16x32_bf16(ahi, bhi1, acc1, 0, 0, 0);
            acc1 = __builtin_amdgcn_mfma_f32_16x16x32_bf16(alo, bhi1, acc1, 0, 0, 0);
        }

        // ---- per-wave partial-C into double-buffered redC ----
        if (kg < 2) {
            #pragma unroll
            for (int rr = 0; rr < 4; ++rr) {
                const int mb = kg * 4 + rr;          // batch row 0..7
                redCp[w * 256 + mb * 32 + fr]      = acc0[rr];
                redCp[w * 256 + mb * 32 + 16 + fr] = acc1[rr];
            }
        }
        __syncthreads();                 // the ONE barrier: redC complete
                                         // (also h-dbuf WAR guard across wgs)

        float sum = redCp[      ob * 32 + oj] + redCp[256 + ob * 32 + oj]
                  + redCp[512 + ob * 32 + oj] + redCp[768 + ob * 32 + oj];

        float p = wxv + sum;
        p = fminf(fmaxf(p, -15.f), 15.f);
        const float e  = __expf(2.0f * p);
        const float hv = 1.0f - 2.0f / (e + 1.0f);

        // pack hi|lo, stamp tag in lo LSB, fire-and-forget publish
        const unsigned short hib = f32_to_bf16(hv);
        const unsigned short lob = f32_to_bf16(hv - bf16_to_f32(hib));
        unsigned int pk = ((unsigned int)hib << 16) | lob;
        pk = (pk & ~1u) | ptag;
        store_sc4u(hw + (size_t)(bg0 + ob) * H + j0 + oj, pk);

        wxv = wx_next;
    }

    // ---- final projection: out[b][c] = h_final[b] . V[c] + bv[c] ----
    if (m == 0) {
        const unsigned int ftag = ((unsigned)(S + 1) >> 1) & 1u;  // tag(512)=0
        const unsigned int* hf = hbuf;   // S even -> final state in buf0
        const int o = t & 31, part = t >> 5;
        const int pb = o >> 2, c = o & 3;
        const unsigned long long* hrow =
            (const unsigned long long*)(hf + (size_t)(bg0 + pb) * H) + part * 64;
        const float* vrow = Vw + (size_t)c * H + part * 128;
        float partial = 0.f;
        for (int q = 0; q < 64; ++q) {
            unsigned long long vvq = __hip_atomic_load(hrow + q, __ATOMIC_RELAXED,
                                                       __HIP_MEMORY_SCOPE_AGENT);
            while ((((unsigned int)vvq ^ ftag) |
                    ((unsigned int)(vvq >> 32) ^ ftag)) & 1u)
                vvq = __hip_atomic_load(hrow + q, __ATOMIC_RELAXED,
                                        __HIP_MEMORY_SCOPE_AGENT);
            const unsigned int v0 = (unsigned int)vvq;
            const unsigned int v1 = (unsigned int)(vvq >> 32);
            const float h0 = bf16_to_f32((unsigned short)(v0 >> 16))
                           + bf16_to_f32((unsigned short)(v0 & 0xffffu));
            const float h1 = bf16_to_f32((unsigned short)(v1 >> 16))
                           + bf16_to_f32((unsigned short)(v1 & 0xffffu));
            partial += h0 * vrow[2 * q] + h1 * vrow[2 * q + 1];
        }
        __syncthreads();
        redCA[part * 32 + o] = partial;
        __syncthreads();
        if (t < 32) {
            float sv = 0.f;
            #pragma unroll
            for (int pq = 0; pq < 8; ++pq) sv += redCA[pq * 32 + t];
            out[(bg0 + (t >> 2)) * NCLS + (t & 3)] = sv + bv[t & 3];
        }
    }
}

// ---------------------------------------------------------------------------
extern "C" void kernel_launch(void* const* d_in, const int* in_sizes, int n_in,
                              void* d_out, int out_size, void* d_ws, size_t ws_size,
                              hipStream_t stream)
{
    const int*   x   = (const int*)d_in[0];
    const float* emb = (const float*)d_in[1];
    const float* W   = (const float*)d_in[2];
    const float* bw  = (const float*)d_in[3];
    const float* U   = (const float*)d_in[4];
    const float* V   = (const float*)d_in[5];
    const float* bv  = (const float*)d_in[6];
    float* out = (float*)d_out;

    unsigned short* wx = (unsigned short*)d_ws;
    const size_t WX_BYTES = (size_t)S * B * H * sizeof(unsigned short); // 64 MiB
    unsigned int* hbuf = (unsigned int*)((char*)d_ws + WX_BYTES);
    const size_t HB_BYTES = (size_t)2 * B * H * sizeof(unsigned int);   // 512 KiB

    // zero both h buffers every call: gives h0 = 0 AND correct initial tags
    hipMemsetAsync((char*)d_ws + WX_BYTES, 0, HB_BYTES, stream);

    hipLaunchKernelGGL(k_wx_gemm, dim3(256, 8), dim3(256), 0, stream,
                       x, emb, W, bw, wx);
    hipLaunchKernelGGL(k_rnn, dim3(256), dim3(256), 0, stream,
                       wx, U, V, bv, hbuf, out);
}